// Round 1
// baseline (473.016 us; speedup 1.0000x reference)
//
#include <hip/hip_runtime.h>
#include <hip/hip_bf16.h>
#include <stdint.h>

// ERGCNConv on MI355X (gfx950).
// Pipeline: memset | prep(bf16 cvt + W transpose) | hist | scan | scatter(sort by type)
//           | edge gather-GEMM (bf16 MFMA) + atomic scatter into agg
//           | node gather-GEMM fused with +agg, bias, ReLU -> out

#define D 128
#define TRELS 16
#define NTYPES 8

typedef __bf16 bf16x8 __attribute__((ext_vector_type(8)));
typedef float f32x4 __attribute__((ext_vector_type(4)));

__device__ __forceinline__ unsigned short f2bf(float f) {
  union { float f; unsigned u; } v; v.f = f;
  unsigned u = v.u;
  return (unsigned short)((u + 0x7FFFu + ((u >> 16) & 1u)) >> 16);  // RNE
}

// ---------- prep: feats -> bf16; W_edge/W_node -> transposed bf16 [t][n][k] ----------
__global__ void prep_k(const float* __restrict__ feats,
                       const float* __restrict__ We,
                       const float* __restrict__ Wn,
                       unsigned short* __restrict__ featsbf,
                       unsigned short* __restrict__ WeT,
                       unsigned short* __restrict__ WnT,
                       int nfeat) {
  int idx = blockIdx.x * 256 + threadIdx.x;
  if (idx < nfeat) { featsbf[idx] = f2bf(feats[idx]); return; }
  idx -= nfeat;
  if (idx < TRELS * D * D) {
    int t = idx >> 14, rem = idx & 16383;
    int n = rem >> 7, k = rem & 127;
    WeT[idx] = f2bf(We[t * 16384 + k * 128 + n]);   // B^T layout: [n][k]
    return;
  }
  idx -= TRELS * D * D;
  if (idx < NTYPES * D * D) {
    int t = idx >> 14, rem = idx & 16383;
    int n = rem >> 7, k = rem & 127;
    WnT[idx] = f2bf(Wn[t * 16384 + k * 128 + n]);
  }
}

// ---------- hist: cnt[dst*16+et]++, per-type edge/node histograms ----------
__global__ void hist_k(const int* __restrict__ dst, const int* __restrict__ etypes,
                       const int* __restrict__ ntypes, int E, int N,
                       int* __restrict__ cnt, int* __restrict__ ehist, int* __restrict__ nhist) {
  __shared__ int sh_e[TRELS], sh_n[NTYPES];
  int tid = threadIdx.x;
  if (tid < TRELS) sh_e[tid] = 0;
  if (tid < NTYPES) sh_n[tid] = 0;
  __syncthreads();
  int g = blockIdx.x * 256 + tid;
  if (g < E) {
    int t = etypes[g];
    atomicAdd(&cnt[dst[g] * TRELS + t], 1);
    atomicAdd(&sh_e[t], 1);
  }
  if (g < N) atomicAdd(&sh_n[ntypes[g]], 1);
  __syncthreads();
  if (tid < TRELS && sh_e[tid]) atomicAdd(&ehist[tid], sh_e[tid]);
  if (tid < NTYPES && sh_n[tid]) atomicAdd(&nhist[tid], sh_n[tid]);
}

// misc layout (ints): eoff[0..16]=0, etb[17..33], ecur[34..49], ehist[50..65],
//                     noff[66..74], ntb[75..83], ncur[84..91], nhist[92..99]
__global__ void scan_k(int* misc) {
  if (threadIdx.x != 0) return;
  int* eoff = misc;      int* etb = misc + 17; int* ecur = misc + 34; int* ehist = misc + 50;
  int* noff = misc + 66; int* ntb = misc + 75; int* ncur = misc + 84; int* nhist = misc + 92;
  int s = 0, ts = 0;
  for (int t = 0; t < TRELS; ++t) {
    eoff[t] = s; ecur[t] = s; etb[t] = ts;
    s += ehist[t]; ts += (ehist[t] + 127) >> 7;
  }
  eoff[TRELS] = s; etb[TRELS] = ts;
  s = 0; ts = 0;
  for (int t = 0; t < NTYPES; ++t) {
    noff[t] = s; ncur[t] = s; ntb[t] = ts;
    s += nhist[t]; ts += (nhist[t] + 127) >> 7;
  }
  noff[NTYPES] = s; ntb[NTYPES] = ts;
}

// ---------- scatter: counting-sort edge ids by etype, node ids by ntype ----------
__global__ void scatter_k(const int* __restrict__ etypes, const int* __restrict__ ntypes,
                          int E, int N, int* __restrict__ misc,
                          int* __restrict__ esorted, int* __restrict__ nsorted) {
  __shared__ int lc_e[TRELS], lb_e[TRELS], lc_n[NTYPES], lb_n[NTYPES];
  int tid = threadIdx.x;
  if (tid < TRELS) lc_e[tid] = 0;
  if (tid < NTYPES) lc_n[tid] = 0;
  __syncthreads();
  int g = blockIdx.x * 256 + tid;
  int te = -1, ide = 0, tn = -1, idn = 0;
  if (g < E) { te = etypes[g]; ide = atomicAdd(&lc_e[te], 1); }
  if (g < N) { tn = ntypes[g]; idn = atomicAdd(&lc_n[tn], 1); }
  __syncthreads();
  if (tid < TRELS && lc_e[tid]) lb_e[tid] = atomicAdd(&misc[34 + tid], lc_e[tid]);
  if (tid < NTYPES && lc_n[tid]) lb_n[tid] = atomicAdd(&misc[84 + tid], lc_n[tid]);
  __syncthreads();
  if (g < E) esorted[lb_e[te] + ide] = g;
  if (g < N) nsorted[lb_n[tn] + idn] = g;
}

// ---------- edge gather-GEMM: msg = (feats[src] @ W_t + b_t)/cnt, atomic add into agg ----------
// Block: 128 edges x 128 out-features, K=128, bf16 MFMA 16x16x32.
// A (gathered feats) in LDS, XOR-swizzled 16B chunks (stride 256B, balanced banks).
// B fragments held in registers, loaded from L2-resident pre-transposed WeT.
__global__ __launch_bounds__(256) void edge_gemm_k(
    const unsigned short* __restrict__ featsbf,
    const unsigned short* __restrict__ WeT,
    const float* __restrict__ b_edge,
    const int* __restrict__ src, const int* __restrict__ dst,
    const int* __restrict__ esorted, const int* __restrict__ misc,
    const int* __restrict__ cnt,
    float* __restrict__ agg) {
  __shared__ unsigned char Asm[128 * 256];
  __shared__ float sm_inv[128];
  __shared__ int sm_dst[128];
  __shared__ int s_etb[17];
  int tid = threadIdx.x;
  if (tid < 17) s_etb[tid] = misc[17 + tid];
  __syncthreads();
  int bid = blockIdx.x;
  if (bid >= s_etb[16]) return;
  int t = 0;
  while (bid >= s_etb[t + 1]) ++t;
  int tile = bid - s_etb[t];
  int eoff_t = misc[t];
  int cntT = misc[t + 1] - eoff_t;

  int lane = tid & 63, w = tid >> 6;
  int m = lane & 15, q = lane >> 4;
  int rw = (w & 1) * 64, cw = (w >> 1) * 64;

  // B fragments: B[k][n] = W[t][k][n]; stored WeT[t][n][k]; lane: n = cw+j*16+m, k = ks*32+q*8..+7
  const unsigned short* WB = WeT + t * (D * D);
  bf16x8 bfr[4][4];
#pragma unroll
  for (int ks = 0; ks < 4; ++ks)
#pragma unroll
    for (int j = 0; j < 4; ++j)
      bfr[ks][j] = *reinterpret_cast<const bf16x8*>(WB + (cw + j * 16 + m) * D + ks * 32 + q * 8);

  // stage A rows (2 threads per edge row) + per-row meta
  int r = tid >> 1, h = tid & 1;
  int gidx = tile * 128 + r;
  bool rv = gidx < cntT;
  int e = 0, sn = 0;
  if (rv) { e = esorted[eoff_t + gidx]; sn = src[e]; }
  if (h == 0) {
    if (rv) {
      int dv = dst[e];
      sm_dst[r] = dv;
      sm_inv[r] = 1.0f / (float)cnt[dv * TRELS + t];
    } else { sm_dst[r] = 0; sm_inv[r] = 0.0f; }
  }
  if (rv) {
    const uint4* gp = reinterpret_cast<const uint4*>(featsbf + (size_t)sn * D);
#pragma unroll
    for (int cc = 0; cc < 8; ++cc) {
      int c = h * 8 + cc;
      *reinterpret_cast<uint4*>(&Asm[r * 256 + ((c ^ (r & 7)) << 4)]) = gp[c];
    }
  }
  __syncthreads();

  f32x4 acc[4][4];
#pragma unroll
  for (int i = 0; i < 4; ++i)
#pragma unroll
    for (int j = 0; j < 4; ++j) acc[i][j] = (f32x4){0.f, 0.f, 0.f, 0.f};

#pragma unroll
  for (int ks = 0; ks < 4; ++ks) {
    bf16x8 a[4];
#pragma unroll
    for (int i = 0; i < 4; ++i) {
      int rr = rw + i * 16 + m;
      int c = ks * 4 + q;
      a[i] = *reinterpret_cast<const bf16x8*>(&Asm[rr * 256 + ((c ^ (rr & 7)) << 4)]);
    }
#pragma unroll
    for (int i = 0; i < 4; ++i)
#pragma unroll
      for (int j = 0; j < 4; ++j)
        acc[i][j] = __builtin_amdgcn_mfma_f32_16x16x32_bf16(a[i], bfr[ks][j], acc[i][j], 0, 0, 0);
  }

  // epilogue: msg = (acc + b_edge[t][n]) * inv_cnt; atomic scatter to agg[dst]
  const float* be = b_edge + t * D;
  float bev[4];
#pragma unroll
  for (int j = 0; j < 4; ++j) bev[j] = be[cw + j * 16 + m];
#pragma unroll
  for (int i = 0; i < 4; ++i) {
#pragma unroll
    for (int reg = 0; reg < 4; ++reg) {
      int rr = rw + i * 16 + q * 4 + reg;  // C/D: row = quad*4+reg, col = m
      float inv = sm_inv[rr];
      if (inv != 0.f) {
        float* arow = agg + (size_t)sm_dst[rr] * D;
#pragma unroll
        for (int j = 0; j < 4; ++j) {
          int n = cw + j * 16 + m;
          atomicAdd(&arow[n], (acc[i][j][reg] + bev[j]) * inv);
        }
      }
    }
  }
}

// ---------- node gather-GEMM fused epilogue: out = relu(feats@Wn[tn] + bn[tn] + agg) ----------
__global__ __launch_bounds__(256) void node_gemm_k(
    const unsigned short* __restrict__ featsbf,
    const unsigned short* __restrict__ WnT,
    const float* __restrict__ b_node,
    const int* __restrict__ nsorted, const int* __restrict__ misc,
    const float* __restrict__ agg,
    float* __restrict__ out) {
  __shared__ unsigned char Asm[128 * 256];
  __shared__ int sm_node[128];
  __shared__ int s_ntb[9];
  int tid = threadIdx.x;
  if (tid < 9) s_ntb[tid] = misc[75 + tid];
  __syncthreads();
  int bid = blockIdx.x;
  if (bid >= s_ntb[8]) return;
  int t = 0;
  while (bid >= s_ntb[t + 1]) ++t;
  int tile = bid - s_ntb[t];
  int noff_t = misc[66 + t];
  int cntT = misc[66 + t + 1] - noff_t;

  int lane = tid & 63, w = tid >> 6;
  int m = lane & 15, q = lane >> 4;
  int rw = (w & 1) * 64, cw = (w >> 1) * 64;

  const unsigned short* WB = WnT + t * (D * D);
  bf16x8 bfr[4][4];
#pragma unroll
  for (int ks = 0; ks < 4; ++ks)
#pragma unroll
    for (int j = 0; j < 4; ++j)
      bfr[ks][j] = *reinterpret_cast<const bf16x8*>(WB + (cw + j * 16 + m) * D + ks * 32 + q * 8);

  int r = tid >> 1, h = tid & 1;
  int gidx = tile * 128 + r;
  bool rv = gidx < cntT;
  int node = 0;
  if (rv) node = nsorted[noff_t + gidx];
  if (h == 0) sm_node[r] = rv ? node : -1;
  if (rv) {
    const uint4* gp = reinterpret_cast<const uint4*>(featsbf + (size_t)node * D);
#pragma unroll
    for (int cc = 0; cc < 8; ++cc) {
      int c = h * 8 + cc;
      *reinterpret_cast<uint4*>(&Asm[r * 256 + ((c ^ (r & 7)) << 4)]) = gp[c];
    }
  }
  __syncthreads();

  f32x4 acc[4][4];
#pragma unroll
  for (int i = 0; i < 4; ++i)
#pragma unroll
    for (int j = 0; j < 4; ++j) acc[i][j] = (f32x4){0.f, 0.f, 0.f, 0.f};

#pragma unroll
  for (int ks = 0; ks < 4; ++ks) {
    bf16x8 a[4];
#pragma unroll
    for (int i = 0; i < 4; ++i) {
      int rr = rw + i * 16 + m;
      int c = ks * 4 + q;
      a[i] = *reinterpret_cast<const bf16x8*>(&Asm[rr * 256 + ((c ^ (rr & 7)) << 4)]);
    }
#pragma unroll
    for (int i = 0; i < 4; ++i)
#pragma unroll
      for (int j = 0; j < 4; ++j)
        acc[i][j] = __builtin_amdgcn_mfma_f32_16x16x32_bf16(a[i], bfr[ks][j], acc[i][j], 0, 0, 0);
  }

  const float* bn = b_node + t * D;
  float bnv[4];
#pragma unroll
  for (int j = 0; j < 4; ++j) bnv[j] = bn[cw + j * 16 + m];
#pragma unroll
  for (int i = 0; i < 4; ++i) {
#pragma unroll
    for (int reg = 0; reg < 4; ++reg) {
      int rr = rw + i * 16 + q * 4 + reg;
      int nd = sm_node[rr];
      if (nd >= 0) {
        const float* arow = agg + (size_t)nd * D;
        float* orow = out + (size_t)nd * D;
#pragma unroll
        for (int j = 0; j < 4; ++j) {
          int n = cw + j * 16 + m;
          float v = acc[i][j][reg] + bnv[j] + arow[n];
          orow[n] = fmaxf(v, 0.f);
        }
      }
    }
  }
}

extern "C" void kernel_launch(void* const* d_in, const int* in_sizes, int n_in,
                              void* d_out, int out_size, void* d_ws, size_t ws_size,
                              hipStream_t stream) {
  const float* feats  = (const float*)d_in[0];
  const float* W_edge = (const float*)d_in[1];
  const float* b_edge = (const float*)d_in[2];
  const float* W_node = (const float*)d_in[3];
  const float* b_node = (const float*)d_in[4];
  const int* src    = (const int*)d_in[5];
  const int* dst    = (const int*)d_in[6];
  const int* ntypes = (const int*)d_in[7];
  const int* etypes = (const int*)d_in[8];
  int N = in_sizes[0] / D;   // 50000
  int E = in_sizes[5];       // 640000

  char* ws = (char*)d_ws;
  size_t off_agg = 0;
  size_t off_cnt = off_agg + (size_t)N * D * 4;          // agg: N*D f32
  size_t off_misc = off_cnt + (size_t)N * TRELS * 4;     // cnt: N*T i32
  size_t zend = off_misc + 512;                          // misc: 128 ints
  size_t off_es = zend;
  size_t off_ns = off_es + (size_t)E * 4;
  size_t off_fb = off_ns + (size_t)N * 4;
  size_t off_we = off_fb + (size_t)N * D * 2;
  size_t off_wn = off_we + (size_t)TRELS * D * D * 2;

  float* agg = (float*)(ws + off_agg);
  int* cnt = (int*)(ws + off_cnt);
  int* misc = (int*)(ws + off_misc);
  int* esorted = (int*)(ws + off_es);
  int* nsorted = (int*)(ws + off_ns);
  unsigned short* featsbf = (unsigned short*)(ws + off_fb);
  unsigned short* WeT = (unsigned short*)(ws + off_we);
  unsigned short* WnT = (unsigned short*)(ws + off_wn);

  hipMemsetAsync(ws, 0, zend, stream);

  int nfeat = N * D;
  int ptot = nfeat + TRELS * D * D + NTYPES * D * D;
  prep_k<<<(ptot + 255) / 256, 256, 0, stream>>>(feats, W_edge, W_node, featsbf, WeT, WnT, nfeat);

  int hgrid = ((E > N ? E : N) + 255) / 256;
  hist_k<<<hgrid, 256, 0, stream>>>(dst, etypes, ntypes, E, N, cnt, misc + 50, misc + 92);
  scan_k<<<1, 64, 0, stream>>>(misc);
  scatter_k<<<hgrid, 256, 0, stream>>>(etypes, ntypes, E, N, misc, esorted, nsorted);

  int egrid = (E + 127) / 128 + TRELS;
  edge_gemm_k<<<egrid, 256, 0, stream>>>(featsbf, WeT, b_edge, src, dst, esorted, misc, cnt, agg);

  int ngrid = (N + 127) / 128 + NTYPES;
  node_gemm_k<<<ngrid, 256, 0, stream>>>(featsbf, WnT, b_node, nsorted, misc, agg, (float*)d_out);
}

// Round 2
// 380.498 us; speedup vs baseline: 1.2432x; 1.2432x over previous
//
#include <hip/hip_runtime.h>
#include <hip/hip_bf16.h>
#include <stdint.h>

// ERGCNConv on MI355X (gfx950).
// R1: eliminate fp32 atomic scatter (was 285us, 320MB atomic RMW traffic).
// Pipeline: memset | prep(bf16 cvt + W transpose) | hist(cnt, nhist)
//           | scan1/2/3 (per-dst CSR offsets + node-type offsets)
//           | scatter (edges -> dst-sorted packed keys; nodes -> ntype-sorted)
//           | hw_gemm: hW[et] = feats @ W_et  (dense bf16 MFMA, no gather, no atomics)
//           | agg: per-dst wave gather-reduce over hW rows (no atomics)
//           | node gather-GEMM fused with +agg, bias, ReLU -> out

#define D 128
#define TRELS 16
#define NTYPES 8

typedef __bf16 bf16x8 __attribute__((ext_vector_type(8)));
typedef float f32x4 __attribute__((ext_vector_type(4)));

__device__ __forceinline__ unsigned short f2bf(float f) {
  union { float f; unsigned u; } v; v.f = f;
  unsigned u = v.u;
  return (unsigned short)((u + 0x7FFFu + ((u >> 16) & 1u)) >> 16);  // RNE
}
__device__ __forceinline__ float bf2f(unsigned short h) {
  union { unsigned u; float f; } v; v.u = ((unsigned)h) << 16;
  return v.f;
}

// ---------- prep: feats -> bf16; W_edge/W_node -> transposed bf16 [t][n][k] ----------
__global__ void prep_k(const float* __restrict__ feats,
                       const float* __restrict__ We,
                       const float* __restrict__ Wn,
                       unsigned short* __restrict__ featsbf,
                       unsigned short* __restrict__ WeT,
                       unsigned short* __restrict__ WnT,
                       int nfeat) {
  int idx = blockIdx.x * 256 + threadIdx.x;
  if (idx < nfeat) { featsbf[idx] = f2bf(feats[idx]); return; }
  idx -= nfeat;
  if (idx < TRELS * D * D) {
    int t = idx >> 14, rem = idx & 16383;
    int n = rem >> 7, k = rem & 127;
    WeT[idx] = f2bf(We[t * 16384 + k * 128 + n]);   // B^T layout: [n][k]
    return;
  }
  idx -= TRELS * D * D;
  if (idx < NTYPES * D * D) {
    int t = idx >> 14, rem = idx & 16383;
    int n = rem >> 7, k = rem & 127;
    WnT[idx] = f2bf(Wn[t * 16384 + k * 128 + n]);
  }
}

// ---------- hist: cnt[dst*16+et]++, node-type histogram ----------
__global__ void hist_k(const int* __restrict__ dst, const int* __restrict__ etypes,
                       const int* __restrict__ ntypes, int E, int N,
                       int* __restrict__ cnt, int* __restrict__ nhist) {
  __shared__ int sh_n[NTYPES];
  int tid = threadIdx.x;
  if (tid < NTYPES) sh_n[tid] = 0;
  __syncthreads();
  int g = blockIdx.x * 256 + tid;
  if (g < E) atomicAdd(&cnt[dst[g] * TRELS + etypes[g]], 1);
  if (g < N) atomicAdd(&sh_n[ntypes[g]], 1);
  __syncthreads();
  if (tid < NTYPES && sh_n[tid]) atomicAdd(&nhist[tid], sh_n[tid]);
}

// misc layout (ints): noff[0..8], ntb[9..17], ncur[18..25], nhist[26..33], bsum[64..127]
// ---------- scan1: deg from cnt rows; block-local exclusive scan -> doff; block sums ----------
__global__ void scan1_k(const int* __restrict__ cnt, int* __restrict__ doff,
                        int* __restrict__ bsum, int N) {
  __shared__ int sd[256];
  int b = blockIdx.x, tid = threadIdx.x;
  int base = b * 1024 + tid * 4;
  int v[4]; int tot = 0;
  for (int j = 0; j < 4; ++j) {
    int i = base + j;
    int dg = 0;
    if (i < N) {
      const int* row = cnt + i * TRELS;
#pragma unroll
      for (int et = 0; et < TRELS; ++et) dg += row[et];
    }
    v[j] = tot; tot += dg;
  }
  sd[tid] = tot;
  __syncthreads();
  for (int off = 1; off < 256; off <<= 1) {
    int t = (tid >= off) ? sd[tid - off] : 0;
    __syncthreads();
    sd[tid] += t;
    __syncthreads();
  }
  int excl = sd[tid] - tot;
  for (int j = 0; j < 4; ++j) {
    int i = base + j;
    if (i < N) doff[i] = excl + v[j];
  }
  if (tid == 255) bsum[b] = sd[255];
}

// ---------- scan2: scan block sums; node-type scan ----------
__global__ void scan2_k(int* __restrict__ misc, int* __restrict__ bsum, int nb) {
  if (threadIdx.x != 0) return;
  int run = 0;
  for (int b = 0; b < nb; ++b) { int t = bsum[b]; bsum[b] = run; run += t; }
  int* noff = misc; int* ntb = misc + 9; int* ncur = misc + 18; int* nhist = misc + 26;
  int s = 0, ts = 0;
  for (int t = 0; t < NTYPES; ++t) {
    noff[t] = s; ncur[t] = s; ntb[t] = ts;
    s += nhist[t]; ts += (nhist[t] + 127) >> 7;
  }
  noff[NTYPES] = s; ntb[NTYPES] = ts;
}

// ---------- scan3: add block offsets; init dcur; doff[N] = E ----------
__global__ void scan3_k(int* __restrict__ doff, int* __restrict__ dcur,
                        const int* __restrict__ bsum, int N, int E) {
  int b = blockIdx.x, tid = threadIdx.x;
  int add = bsum[b];
  int base = b * 1024 + tid * 4;
  for (int j = 0; j < 4; ++j) {
    int i = base + j;
    if (i < N) { int o = doff[i] + add; doff[i] = o; dcur[i] = o; }
  }
  if (b == 0 && tid == 0) doff[N] = E;
}

// ---------- scatter: edges -> dst-sorted packed keys; nodes -> ntype-sorted ----------
__global__ void scatter_k(const int* __restrict__ src, const int* __restrict__ dst,
                          const int* __restrict__ etypes, const int* __restrict__ ntypes,
                          int E, int N, int* __restrict__ misc,
                          int* __restrict__ dcur,
                          int* __restrict__ edst, int* __restrict__ nsorted) {
  __shared__ int lc_n[NTYPES], lb_n[NTYPES];
  int tid = threadIdx.x;
  if (tid < NTYPES) lc_n[tid] = 0;
  __syncthreads();
  int g = blockIdx.x * 256 + tid;
  if (g < E) {
    int d = dst[g];
    int pos = atomicAdd(&dcur[d], 1);
    edst[pos] = src[g] * TRELS + etypes[g];   // packed key
  }
  int tn = -1, idn = 0;
  if (g < N) { tn = ntypes[g]; idn = atomicAdd(&lc_n[tn], 1); }
  __syncthreads();
  if (tid < NTYPES && lc_n[tid]) lb_n[tid] = atomicAdd(&misc[18 + tid], lc_n[tid]);
  __syncthreads();
  if (g < N) nsorted[lb_n[tn] + idn] = g;
}

// ---------- hW GEMM: hW[et] = feats @ W_et (bf16 out), dense, no gather ----------
// Block: 128 rows x 128 cols, K=128, 4 waves each 64x64. A in swizzled LDS, B in regs.
__global__ __launch_bounds__(256) void hw_gemm_k(
    const unsigned short* __restrict__ featsbf,
    const unsigned short* __restrict__ WeT,
    unsigned short* __restrict__ hW, int N) {
  __shared__ unsigned char Asm[128 * 256];
  int tid = threadIdx.x;
  int et = blockIdx.y;
  int tile = blockIdx.x;

  int lane = tid & 63, w = tid >> 6;
  int m = lane & 15, q = lane >> 4;
  int rw = (w & 1) * 64, cw = (w >> 1) * 64;

  const unsigned short* WB = WeT + et * (D * D);
  bf16x8 bfr[4][4];
#pragma unroll
  for (int ks = 0; ks < 4; ++ks)
#pragma unroll
    for (int j = 0; j < 4; ++j)
      bfr[ks][j] = *reinterpret_cast<const bf16x8*>(WB + (cw + j * 16 + m) * D + ks * 32 + q * 8);

  int r = tid >> 1, h = tid & 1;
  int row = tile * 128 + r;
  if (row < N) {
    const uint4* gp = reinterpret_cast<const uint4*>(featsbf + (size_t)row * D);
#pragma unroll
    for (int cc = 0; cc < 8; ++cc) {
      int c = h * 8 + cc;
      *reinterpret_cast<uint4*>(&Asm[r * 256 + ((c ^ (r & 7)) << 4)]) = gp[c];
    }
  }
  __syncthreads();

  f32x4 acc[4][4];
#pragma unroll
  for (int i = 0; i < 4; ++i)
#pragma unroll
    for (int j = 0; j < 4; ++j) acc[i][j] = (f32x4){0.f, 0.f, 0.f, 0.f};

#pragma unroll
  for (int ks = 0; ks < 4; ++ks) {
    bf16x8 a[4];
#pragma unroll
    for (int i = 0; i < 4; ++i) {
      int rr = rw + i * 16 + m;
      int c = ks * 4 + q;
      a[i] = *reinterpret_cast<const bf16x8*>(&Asm[rr * 256 + ((c ^ (rr & 7)) << 4)]);
    }
#pragma unroll
    for (int i = 0; i < 4; ++i)
#pragma unroll
      for (int j = 0; j < 4; ++j)
        acc[i][j] = __builtin_amdgcn_mfma_f32_16x16x32_bf16(a[i], bfr[ks][j], acc[i][j], 0, 0, 0);
  }

  // epilogue: bf16 store (no bias; edge bias folded into agg pass)
#pragma unroll
  for (int i = 0; i < 4; ++i) {
#pragma unroll
    for (int reg = 0; reg < 4; ++reg) {
      int rr = rw + i * 16 + q * 4 + reg;  // C/D: row = quad*4+reg, col = m
      int orow = tile * 128 + rr;
      if (orow < N) {
        unsigned short* op = hW + ((size_t)et * N + orow) * D;
#pragma unroll
        for (int j = 0; j < 4; ++j)
          op[cw + j * 16 + m] = f2bf(acc[i][j][reg]);
      }
    }
  }
}

// ---------- agg: per-dst wave gather-reduce over hW rows; + bias of present etypes ----------
__global__ __launch_bounds__(256) void agg_k(
    const unsigned short* __restrict__ hW,
    const float* __restrict__ b_edge,
    const int* __restrict__ cnt,
    const int* __restrict__ doff, const int* __restrict__ edst,
    float* __restrict__ agg, int N) {
  int tid = threadIdx.x;
  int lane = tid & 63, w = tid >> 6;
  int d = blockIdx.x * 4 + w;
  if (d >= N) return;

  int cv = 0;
  if (lane < TRELS) cv = cnt[d * TRELS + lane];
  float invl = (cv > 0) ? 1.0f / (float)cv : 0.0f;

  int start = doff[d], end = doff[d + 1];
  float ax = 0.f, ay = 0.f;
  for (int base = start; base < end; base += 64) {
    int key = 0;
    if (base + lane < end) key = edst[base + lane];
    int nchunk = end - base; if (nchunk > 64) nchunk = 64;
    for (int j = 0; j < nchunk; ++j) {
      int k = __shfl(key, j, 64);
      int sn = k >> 4, et = k & 15;
      float inv = __shfl(invl, et, 64);
      ushort2 hv = *reinterpret_cast<const ushort2*>(hW + ((size_t)et * N + sn) * D + lane * 2);
      ax += inv * bf2f(hv.x);
      ay += inv * bf2f(hv.y);
    }
  }
  // bias: sum of b_edge[et] over present etypes
#pragma unroll
  for (int et = 0; et < TRELS; ++et) {
    int c = __shfl(cv, et, 64);
    if (c > 0) {
      const float* bp = b_edge + et * D + lane * 2;
      ax += bp[0]; ay += bp[1];
    }
  }
  float2* op = reinterpret_cast<float2*>(agg + (size_t)d * D + lane * 2);
  *op = make_float2(ax, ay);
}

// ---------- node gather-GEMM fused epilogue: out = relu(feats@Wn[tn] + bn[tn] + agg) ----------
__global__ __launch_bounds__(256) void node_gemm_k(
    const unsigned short* __restrict__ featsbf,
    const unsigned short* __restrict__ WnT,
    const float* __restrict__ b_node,
    const int* __restrict__ nsorted, const int* __restrict__ misc,
    const float* __restrict__ agg,
    float* __restrict__ out) {
  __shared__ unsigned char Asm[128 * 256];
  __shared__ int sm_node[128];
  __shared__ int s_ntb[9];
  int tid = threadIdx.x;
  if (tid < 9) s_ntb[tid] = misc[9 + tid];
  __syncthreads();
  int bid = blockIdx.x;
  if (bid >= s_ntb[8]) return;
  int t = 0;
  while (bid >= s_ntb[t + 1]) ++t;
  int tile = bid - s_ntb[t];
  int noff_t = misc[t];
  int cntT = misc[t + 1] - noff_t;

  int lane = tid & 63, w = tid >> 6;
  int m = lane & 15, q = lane >> 4;
  int rw = (w & 1) * 64, cw = (w >> 1) * 64;

  const unsigned short* WB = WnT + t * (D * D);
  bf16x8 bfr[4][4];
#pragma unroll
  for (int ks = 0; ks < 4; ++ks)
#pragma unroll
    for (int j = 0; j < 4; ++j)
      bfr[ks][j] = *reinterpret_cast<const bf16x8*>(WB + (cw + j * 16 + m) * D + ks * 32 + q * 8);

  int r = tid >> 1, h = tid & 1;
  int gidx = tile * 128 + r;
  bool rv = gidx < cntT;
  int node = 0;
  if (rv) node = nsorted[noff_t + gidx];
  if (h == 0) sm_node[r] = rv ? node : -1;
  if (rv) {
    const uint4* gp = reinterpret_cast<const uint4*>(featsbf + (size_t)node * D);
#pragma unroll
    for (int cc = 0; cc < 8; ++cc) {
      int c = h * 8 + cc;
      *reinterpret_cast<uint4*>(&Asm[r * 256 + ((c ^ (r & 7)) << 4)]) = gp[c];
    }
  }
  __syncthreads();

  f32x4 acc[4][4];
#pragma unroll
  for (int i = 0; i < 4; ++i)
#pragma unroll
    for (int j = 0; j < 4; ++j) acc[i][j] = (f32x4){0.f, 0.f, 0.f, 0.f};

#pragma unroll
  for (int ks = 0; ks < 4; ++ks) {
    bf16x8 a[4];
#pragma unroll
    for (int i = 0; i < 4; ++i) {
      int rr = rw + i * 16 + m;
      int c = ks * 4 + q;
      a[i] = *reinterpret_cast<const bf16x8*>(&Asm[rr * 256 + ((c ^ (rr & 7)) << 4)]);
    }
#pragma unroll
    for (int i = 0; i < 4; ++i)
#pragma unroll
      for (int j = 0; j < 4; ++j)
        acc[i][j] = __builtin_amdgcn_mfma_f32_16x16x32_bf16(a[i], bfr[ks][j], acc[i][j], 0, 0, 0);
  }

  const float* bn = b_node + t * D;
  float bnv[4];
#pragma unroll
  for (int j = 0; j < 4; ++j) bnv[j] = bn[cw + j * 16 + m];
#pragma unroll
  for (int i = 0; i < 4; ++i) {
#pragma unroll
    for (int reg = 0; reg < 4; ++reg) {
      int rr = rw + i * 16 + q * 4 + reg;
      int nd = sm_node[rr];
      if (nd >= 0) {
        const float* arow = agg + (size_t)nd * D;
        float* orow = out + (size_t)nd * D;
#pragma unroll
        for (int j = 0; j < 4; ++j) {
          int n = cw + j * 16 + m;
          float v = acc[i][j][reg] + bnv[j] + arow[n];
          orow[n] = fmaxf(v, 0.f);
        }
      }
    }
  }
}

static inline size_t align256(size_t x) { return (x + 255) & ~(size_t)255; }

extern "C" void kernel_launch(void* const* d_in, const int* in_sizes, int n_in,
                              void* d_out, int out_size, void* d_ws, size_t ws_size,
                              hipStream_t stream) {
  const float* feats  = (const float*)d_in[0];
  const float* W_edge = (const float*)d_in[1];
  const float* b_edge = (const float*)d_in[2];
  const float* W_node = (const float*)d_in[3];
  const float* b_node = (const float*)d_in[4];
  const int* src    = (const int*)d_in[5];
  const int* dst    = (const int*)d_in[6];
  const int* ntypes = (const int*)d_in[7];
  const int* etypes = (const int*)d_in[8];
  int N = in_sizes[0] / D;   // 50000
  int E = in_sizes[5];       // 640000

  char* ws = (char*)d_ws;
  size_t o_cnt  = 0;
  size_t o_misc = align256(o_cnt + (size_t)N * TRELS * 4);
  size_t zend   = align256(o_misc + 512);
  size_t o_doff = zend;
  size_t o_dcur = align256(o_doff + (size_t)(N + 1) * 4);
  size_t o_edst = align256(o_dcur + (size_t)N * 4);
  size_t o_ns   = align256(o_edst + (size_t)E * 4);
  size_t o_fb   = align256(o_ns + (size_t)N * 4);
  size_t o_we   = align256(o_fb + (size_t)N * D * 2);
  size_t o_wn   = align256(o_we + (size_t)TRELS * D * D * 2);
  size_t o_agg  = align256(o_wn + (size_t)NTYPES * D * D * 2);
  size_t o_hw   = align256(o_agg + (size_t)N * D * 4);

  int* cnt = (int*)(ws + o_cnt);
  int* misc = (int*)(ws + o_misc);
  int* doff = (int*)(ws + o_doff);
  int* dcur = (int*)(ws + o_dcur);
  int* edst = (int*)(ws + o_edst);
  int* nsorted = (int*)(ws + o_ns);
  unsigned short* featsbf = (unsigned short*)(ws + o_fb);
  unsigned short* WeT = (unsigned short*)(ws + o_we);
  unsigned short* WnT = (unsigned short*)(ws + o_wn);
  float* agg = (float*)(ws + o_agg);
  unsigned short* hW = (unsigned short*)(ws + o_hw);
  int* bsum = misc + 64;

  hipMemsetAsync(ws, 0, zend, stream);

  int nfeat = N * D;
  int ptot = nfeat + TRELS * D * D + NTYPES * D * D;
  prep_k<<<(ptot + 255) / 256, 256, 0, stream>>>(feats, W_edge, W_node, featsbf, WeT, WnT, nfeat);

  int hgrid = ((E > N ? E : N) + 255) / 256;
  hist_k<<<hgrid, 256, 0, stream>>>(dst, etypes, ntypes, E, N, cnt, misc + 26);

  int nb = (N + 1023) / 1024;
  scan1_k<<<nb, 256, 0, stream>>>(cnt, doff, bsum, N);
  scan2_k<<<1, 64, 0, stream>>>(misc, bsum, nb);
  scan3_k<<<nb, 256, 0, stream>>>(doff, dcur, bsum, N, E);

  scatter_k<<<hgrid, 256, 0, stream>>>(src, dst, etypes, ntypes, E, N, misc, dcur, edst, nsorted);

  int mtiles = (N + 127) / 128;
  dim3 ggrid(mtiles, TRELS);
  hw_gemm_k<<<ggrid, 256, 0, stream>>>(featsbf, WeT, hW, N);

  agg_k<<<(N + 3) / 4, 256, 0, stream>>>(hW, b_edge, cnt, doff, edst, agg, N);

  int ngrid = mtiles + NTYPES;
  node_gemm_k<<<ngrid, 256, 0, stream>>>(featsbf, WnT, b_node, nsorted, misc, agg, (float*)d_out);
}

// Round 3
// 339.285 us; speedup vs baseline: 1.3942x; 1.1215x over previous
//
#include <hip/hip_runtime.h>
#include <hip/hip_bf16.h>
#include <stdint.h>

// ERGCNConv on MI355X (gfx950).
// R2: fix epilogues (LDS repack -> coalesced dwordx4 stores) + agg MLP unroll.
// Pipeline: memset | prep(bf16 cvt + W transpose) | hist(cnt, nhist)
//           | scan1/2/3 (per-dst CSR offsets + node-type offsets)
//           | scatter (edges -> dst-sorted packed keys; nodes -> ntype-sorted)
//           | hw_gemm: hW[et] = feats @ W_et  (dense bf16 MFMA, LDS-repacked store)
//           | agg: per-dst wave gather-reduce over hW rows (4-way unrolled)
//           | node gather-GEMM, LDS-repacked epilogue fused with +agg, bias, ReLU

#define D 128
#define TRELS 16
#define NTYPES 8

typedef __bf16 bf16x8 __attribute__((ext_vector_type(8)));
typedef float f32x4 __attribute__((ext_vector_type(4)));

__device__ __forceinline__ unsigned short f2bf(float f) {
  union { float f; unsigned u; } v; v.f = f;
  unsigned u = v.u;
  return (unsigned short)((u + 0x7FFFu + ((u >> 16) & 1u)) >> 16);  // RNE
}
__device__ __forceinline__ float bf2f(unsigned short h) {
  union { unsigned u; float f; } v; v.u = ((unsigned)h) << 16;
  return v.f;
}

// ---------- prep: feats -> bf16; W_edge/W_node -> transposed bf16 [t][n][k] ----------
__global__ void prep_k(const float* __restrict__ feats,
                       const float* __restrict__ We,
                       const float* __restrict__ Wn,
                       unsigned short* __restrict__ featsbf,
                       unsigned short* __restrict__ WeT,
                       unsigned short* __restrict__ WnT,
                       int nfeat) {
  int idx = blockIdx.x * 256 + threadIdx.x;
  if (idx < nfeat) { featsbf[idx] = f2bf(feats[idx]); return; }
  idx -= nfeat;
  if (idx < TRELS * D * D) {
    int t = idx >> 14, rem = idx & 16383;
    int n = rem >> 7, k = rem & 127;
    WeT[idx] = f2bf(We[t * 16384 + k * 128 + n]);   // B^T layout: [n][k]
    return;
  }
  idx -= TRELS * D * D;
  if (idx < NTYPES * D * D) {
    int t = idx >> 14, rem = idx & 16383;
    int n = rem >> 7, k = rem & 127;
    WnT[idx] = f2bf(Wn[t * 16384 + k * 128 + n]);
  }
}

// ---------- hist: cnt[dst*16+et]++, node-type histogram ----------
__global__ void hist_k(const int* __restrict__ dst, const int* __restrict__ etypes,
                       const int* __restrict__ ntypes, int E, int N,
                       int* __restrict__ cnt, int* __restrict__ nhist) {
  __shared__ int sh_n[NTYPES];
  int tid = threadIdx.x;
  if (tid < NTYPES) sh_n[tid] = 0;
  __syncthreads();
  int g = blockIdx.x * 256 + tid;
  if (g < E) atomicAdd(&cnt[dst[g] * TRELS + etypes[g]], 1);
  if (g < N) atomicAdd(&sh_n[ntypes[g]], 1);
  __syncthreads();
  if (tid < NTYPES && sh_n[tid]) atomicAdd(&nhist[tid], sh_n[tid]);
}

// misc layout (ints): noff[0..8], ntb[9..17], ncur[18..25], nhist[26..33], bsum[64..127]
// ---------- scan1: deg from cnt rows; block-local exclusive scan -> doff; block sums ----------
__global__ void scan1_k(const int* __restrict__ cnt, int* __restrict__ doff,
                        int* __restrict__ bsum, int N) {
  __shared__ int sd[256];
  int b = blockIdx.x, tid = threadIdx.x;
  int base = b * 1024 + tid * 4;
  int v[4]; int tot = 0;
  for (int j = 0; j < 4; ++j) {
    int i = base + j;
    int dg = 0;
    if (i < N) {
      const int* row = cnt + i * TRELS;
#pragma unroll
      for (int et = 0; et < TRELS; ++et) dg += row[et];
    }
    v[j] = tot; tot += dg;
  }
  sd[tid] = tot;
  __syncthreads();
  for (int off = 1; off < 256; off <<= 1) {
    int t = (tid >= off) ? sd[tid - off] : 0;
    __syncthreads();
    sd[tid] += t;
    __syncthreads();
  }
  int excl = sd[tid] - tot;
  for (int j = 0; j < 4; ++j) {
    int i = base + j;
    if (i < N) doff[i] = excl + v[j];
  }
  if (tid == 255) bsum[b] = sd[255];
}

// ---------- scan2: scan block sums; node-type scan ----------
__global__ void scan2_k(int* __restrict__ misc, int* __restrict__ bsum, int nb) {
  if (threadIdx.x != 0) return;
  int run = 0;
  for (int b = 0; b < nb; ++b) { int t = bsum[b]; bsum[b] = run; run += t; }
  int* noff = misc; int* ntb = misc + 9; int* ncur = misc + 18; int* nhist = misc + 26;
  int s = 0, ts = 0;
  for (int t = 0; t < NTYPES; ++t) {
    noff[t] = s; ncur[t] = s; ntb[t] = ts;
    s += nhist[t]; ts += (nhist[t] + 127) >> 7;
  }
  noff[NTYPES] = s; ntb[NTYPES] = ts;
}

// ---------- scan3: add block offsets; init dcur; doff[N] = E ----------
__global__ void scan3_k(int* __restrict__ doff, int* __restrict__ dcur,
                        const int* __restrict__ bsum, int N, int E) {
  int b = blockIdx.x, tid = threadIdx.x;
  int add = bsum[b];
  int base = b * 1024 + tid * 4;
  for (int j = 0; j < 4; ++j) {
    int i = base + j;
    if (i < N) { int o = doff[i] + add; doff[i] = o; dcur[i] = o; }
  }
  if (b == 0 && tid == 0) doff[N] = E;
}

// ---------- scatter: edges -> dst-sorted packed keys; nodes -> ntype-sorted ----------
__global__ void scatter_k(const int* __restrict__ src, const int* __restrict__ dst,
                          const int* __restrict__ etypes, const int* __restrict__ ntypes,
                          int E, int N, int* __restrict__ misc,
                          int* __restrict__ dcur,
                          int* __restrict__ edst, int* __restrict__ nsorted) {
  __shared__ int lc_n[NTYPES], lb_n[NTYPES];
  int tid = threadIdx.x;
  if (tid < NTYPES) lc_n[tid] = 0;
  __syncthreads();
  int g = blockIdx.x * 256 + tid;
  if (g < E) {
    int d = dst[g];
    int pos = atomicAdd(&dcur[d], 1);
    edst[pos] = src[g] * TRELS + etypes[g];   // packed key
  }
  int tn = -1, idn = 0;
  if (g < N) { tn = ntypes[g]; idn = atomicAdd(&lc_n[tn], 1); }
  __syncthreads();
  if (tid < NTYPES && lc_n[tid]) lb_n[tid] = atomicAdd(&misc[18 + tid], lc_n[tid]);
  __syncthreads();
  if (g < N) nsorted[lb_n[tn] + idn] = g;
}

// ---------- hW GEMM: hW[et] = feats @ W_et (bf16 out), dense, no gather ----------
// Block: 128 rows x 128 cols, K=128, 4 waves each 64x64. A in swizzled LDS, B in regs.
// Epilogue: C -> LDS bf16 (pitch 132 shorts), coalesced dwordx4 readout.
__global__ __launch_bounds__(256) void hw_gemm_k(
    const unsigned short* __restrict__ featsbf,
    const unsigned short* __restrict__ WeT,
    unsigned short* __restrict__ hW, int N) {
  __shared__ unsigned char Asm[128 * 264];
  int tid = threadIdx.x;
  int et = blockIdx.y;
  int tile = blockIdx.x;

  int lane = tid & 63, w = tid >> 6;
  int m = lane & 15, q = lane >> 4;
  int rw = (w & 1) * 64, cw = (w >> 1) * 64;

  const unsigned short* WB = WeT + et * (D * D);
  bf16x8 bfr[4][4];
#pragma unroll
  for (int ks = 0; ks < 4; ++ks)
#pragma unroll
    for (int j = 0; j < 4; ++j)
      bfr[ks][j] = *reinterpret_cast<const bf16x8*>(WB + (cw + j * 16 + m) * D + ks * 32 + q * 8);

  int r = tid >> 1, h = tid & 1;
  int row = tile * 128 + r;
  if (row < N) {
    const uint4* gp = reinterpret_cast<const uint4*>(featsbf + (size_t)row * D);
#pragma unroll
    for (int cc = 0; cc < 8; ++cc) {
      int c = h * 8 + cc;
      *reinterpret_cast<uint4*>(&Asm[r * 256 + ((c ^ (r & 7)) << 4)]) = gp[c];
    }
  }
  __syncthreads();

  f32x4 acc[4][4];
#pragma unroll
  for (int i = 0; i < 4; ++i)
#pragma unroll
    for (int j = 0; j < 4; ++j) acc[i][j] = (f32x4){0.f, 0.f, 0.f, 0.f};

#pragma unroll
  for (int ks = 0; ks < 4; ++ks) {
    bf16x8 a[4];
#pragma unroll
    for (int i = 0; i < 4; ++i) {
      int rr = rw + i * 16 + m;
      int c = ks * 4 + q;
      a[i] = *reinterpret_cast<const bf16x8*>(&Asm[rr * 256 + ((c ^ (rr & 7)) << 4)]);
    }
#pragma unroll
    for (int i = 0; i < 4; ++i)
#pragma unroll
      for (int j = 0; j < 4; ++j)
        acc[i][j] = __builtin_amdgcn_mfma_f32_16x16x32_bf16(a[i], bfr[ks][j], acc[i][j], 0, 0, 0);
  }

  // epilogue: C -> LDS bf16 tile (pitch 132 shorts = 264 B), then coalesced stores
  __syncthreads();
  unsigned short* Cs = reinterpret_cast<unsigned short*>(Asm);
#pragma unroll
  for (int i = 0; i < 4; ++i)
#pragma unroll
    for (int j = 0; j < 4; ++j)
#pragma unroll
      for (int reg = 0; reg < 4; ++reg) {
        int rr = rw + i * 16 + q * 4 + reg;  // C/D: row = quad*4+reg, col = m
        Cs[rr * 132 + cw + j * 16 + m] = f2bf(acc[i][j][reg]);
      }
  __syncthreads();
  char* gout = (char*)(hW + ((size_t)et * N + (size_t)tile * 128) * D);
#pragma unroll
  for (int cp = 0; cp < 8; ++cp) {
    int o = cp * 4096 + tid * 16;     // byte offset in logical 128x256B tile
    int rloc = o >> 8;
    if (tile * 128 + rloc < N) {
      uint4 v = *reinterpret_cast<const uint4*>(&Asm[rloc * 264 + (o & 255)]);
      *reinterpret_cast<uint4*>(gout + o) = v;
    }
  }
}

// ---------- agg: per-dst wave gather-reduce over hW rows; + bias of present etypes ----------
__global__ __launch_bounds__(256) void agg_k(
    const unsigned short* __restrict__ hW,
    const float* __restrict__ b_edge,
    const int* __restrict__ cnt,
    const int* __restrict__ doff, const int* __restrict__ edst,
    float* __restrict__ agg, int N) {
  int tid = threadIdx.x;
  int lane = tid & 63, w = tid >> 6;
  int d = blockIdx.x * 4 + w;
  if (d >= N) return;

  int cv = 0;
  if (lane < TRELS) cv = cnt[d * TRELS + lane];
  float invl = (cv > 0) ? 1.0f / (float)cv : 0.0f;

  int start = doff[d], end = doff[d + 1];
  float ax = 0.f, ay = 0.f;
  for (int base = start; base < end; base += 64) {
    int key = 0;
    if (base + lane < end) key = edst[base + lane];
    int nchunk = end - base; if (nchunk > 64) nchunk = 64;
    int j = 0;
    for (; j + 4 <= nchunk; j += 4) {
      int k0 = __shfl(key, j, 64), k1 = __shfl(key, j + 1, 64);
      int k2 = __shfl(key, j + 2, 64), k3 = __shfl(key, j + 3, 64);
      float i0 = __shfl(invl, k0 & 15, 64), i1 = __shfl(invl, k1 & 15, 64);
      float i2 = __shfl(invl, k2 & 15, 64), i3 = __shfl(invl, k3 & 15, 64);
      ushort2 h0 = *reinterpret_cast<const ushort2*>(hW + ((size_t)(k0 & 15) * N + (k0 >> 4)) * D + lane * 2);
      ushort2 h1 = *reinterpret_cast<const ushort2*>(hW + ((size_t)(k1 & 15) * N + (k1 >> 4)) * D + lane * 2);
      ushort2 h2 = *reinterpret_cast<const ushort2*>(hW + ((size_t)(k2 & 15) * N + (k2 >> 4)) * D + lane * 2);
      ushort2 h3 = *reinterpret_cast<const ushort2*>(hW + ((size_t)(k3 & 15) * N + (k3 >> 4)) * D + lane * 2);
      ax += i0 * bf2f(h0.x); ay += i0 * bf2f(h0.y);
      ax += i1 * bf2f(h1.x); ay += i1 * bf2f(h1.y);
      ax += i2 * bf2f(h2.x); ay += i2 * bf2f(h2.y);
      ax += i3 * bf2f(h3.x); ay += i3 * bf2f(h3.y);
    }
    for (; j < nchunk; ++j) {
      int k = __shfl(key, j, 64);
      float inv = __shfl(invl, k & 15, 64);
      ushort2 hv = *reinterpret_cast<const ushort2*>(hW + ((size_t)(k & 15) * N + (k >> 4)) * D + lane * 2);
      ax += inv * bf2f(hv.x); ay += inv * bf2f(hv.y);
    }
  }
  // bias: sum of b_edge[et] over present etypes
#pragma unroll
  for (int et = 0; et < TRELS; ++et) {
    int c = __shfl(cv, et, 64);
    if (c > 0) {
      const float* bp = b_edge + et * D + lane * 2;
      ax += bp[0]; ay += bp[1];
    }
  }
  float2* op = reinterpret_cast<float2*>(agg + (size_t)d * D + lane * 2);
  *op = make_float2(ax, ay);
}

// ---------- node gather-GEMM: out = relu(feats@Wn[tn] + bn[tn] + agg) ----------
// Epilogue: two fp32 half-tile passes through LDS, fused agg+bias+relu on coalesced readout.
__global__ __launch_bounds__(256) void node_gemm_k(
    const unsigned short* __restrict__ featsbf,
    const unsigned short* __restrict__ WnT,
    const float* __restrict__ b_node,
    const int* __restrict__ nsorted, const int* __restrict__ misc,
    const float* __restrict__ agg,
    float* __restrict__ out) {
  __shared__ unsigned char Asm[128 * 264];
  __shared__ int sm_node[128];
  __shared__ int s_ntb[9];
  int tid = threadIdx.x;
  if (tid < 9) s_ntb[tid] = misc[9 + tid];
  __syncthreads();
  int bid = blockIdx.x;
  if (bid >= s_ntb[8]) return;
  int t = 0;
  while (bid >= s_ntb[t + 1]) ++t;
  int tile = bid - s_ntb[t];
  int noff_t = misc[t];
  int cntT = misc[t + 1] - noff_t;

  int lane = tid & 63, w = tid >> 6;
  int m = lane & 15, q = lane >> 4;
  int rw = (w & 1) * 64, cw = (w >> 1) * 64;

  const unsigned short* WB = WnT + t * (D * D);
  bf16x8 bfr[4][4];
#pragma unroll
  for (int ks = 0; ks < 4; ++ks)
#pragma unroll
    for (int j = 0; j < 4; ++j)
      bfr[ks][j] = *reinterpret_cast<const bf16x8*>(WB + (cw + j * 16 + m) * D + ks * 32 + q * 8);

  int r = tid >> 1, h = tid & 1;
  int gidx = tile * 128 + r;
  bool rv = gidx < cntT;
  int node = 0;
  if (rv) node = nsorted[noff_t + gidx];
  if (h == 0) sm_node[r] = rv ? node : -1;
  if (rv) {
    const uint4* gp = reinterpret_cast<const uint4*>(featsbf + (size_t)node * D);
#pragma unroll
    for (int cc = 0; cc < 8; ++cc) {
      int c = h * 8 + cc;
      *reinterpret_cast<uint4*>(&Asm[r * 256 + ((c ^ (r & 7)) << 4)]) = gp[c];
    }
  }
  __syncthreads();

  f32x4 acc[4][4];
#pragma unroll
  for (int i = 0; i < 4; ++i)
#pragma unroll
    for (int j = 0; j < 4; ++j) acc[i][j] = (f32x4){0.f, 0.f, 0.f, 0.f};

#pragma unroll
  for (int ks = 0; ks < 4; ++ks) {
    bf16x8 a[4];
#pragma unroll
    for (int i = 0; i < 4; ++i) {
      int rr = rw + i * 16 + m;
      int c = ks * 4 + q;
      a[i] = *reinterpret_cast<const bf16x8*>(&Asm[rr * 256 + ((c ^ (rr & 7)) << 4)]);
    }
#pragma unroll
    for (int i = 0; i < 4; ++i)
#pragma unroll
      for (int j = 0; j < 4; ++j)
        acc[i][j] = __builtin_amdgcn_mfma_f32_16x16x32_bf16(a[i], bfr[ks][j], acc[i][j], 0, 0, 0);
  }

  // epilogue: two half-tile fp32 passes through LDS (pitch 132 floats = 528 B, 64 rows)
  const float* bnp = b_node + t * D;
  float* Cf = reinterpret_cast<float*>(Asm);
  __syncthreads();
#pragma unroll
  for (int half = 0; half < 2; ++half) {
    if ((w & 1) == half) {
#pragma unroll
      for (int i = 0; i < 4; ++i)
#pragma unroll
        for (int j = 0; j < 4; ++j)
#pragma unroll
          for (int reg = 0; reg < 4; ++reg) {
            int rl = i * 16 + q * 4 + reg;   // local row 0..63
            Cf[rl * 132 + cw + j * 16 + m] = acc[i][j][reg];
          }
    }
    __syncthreads();
#pragma unroll
    for (int cp = 0; cp < 8; ++cp) {
      int o = cp * 4096 + tid * 16;     // byte offset in 64x512B half tile
      int rl = o >> 9;
      int nd = sm_node[half * 64 + rl];
      if (nd >= 0) {
        int col = (o & 511) >> 2;
        f32x4 c = *reinterpret_cast<const f32x4*>((char*)Cf + rl * 528 + (o & 511));
        f32x4 a = *reinterpret_cast<const f32x4*>(agg + (size_t)nd * D + col);
        f32x4 b4 = *reinterpret_cast<const f32x4*>(bnp + col);
        f32x4 res;
#pragma unroll
        for (int z = 0; z < 4; ++z) res[z] = fmaxf(c[z] + a[z] + b4[z], 0.f);
        *reinterpret_cast<f32x4*>(out + (size_t)nd * D + col) = res;
      }
    }
    __syncthreads();
  }
}

static inline size_t align256(size_t x) { return (x + 255) & ~(size_t)255; }

extern "C" void kernel_launch(void* const* d_in, const int* in_sizes, int n_in,
                              void* d_out, int out_size, void* d_ws, size_t ws_size,
                              hipStream_t stream) {
  const float* feats  = (const float*)d_in[0];
  const float* W_edge = (const float*)d_in[1];
  const float* b_edge = (const float*)d_in[2];
  const float* W_node = (const float*)d_in[3];
  const float* b_node = (const float*)d_in[4];
  const int* src    = (const int*)d_in[5];
  const int* dst    = (const int*)d_in[6];
  const int* ntypes = (const int*)d_in[7];
  const int* etypes = (const int*)d_in[8];
  int N = in_sizes[0] / D;   // 50000
  int E = in_sizes[5];       // 640000

  char* ws = (char*)d_ws;
  size_t o_cnt  = 0;
  size_t o_misc = align256(o_cnt + (size_t)N * TRELS * 4);
  size_t zend   = align256(o_misc + 512);
  size_t o_doff = zend;
  size_t o_dcur = align256(o_doff + (size_t)(N + 1) * 4);
  size_t o_edst = align256(o_dcur + (size_t)N * 4);
  size_t o_ns   = align256(o_edst + (size_t)E * 4);
  size_t o_fb   = align256(o_ns + (size_t)N * 4);
  size_t o_we   = align256(o_fb + (size_t)N * D * 2);
  size_t o_wn   = align256(o_we + (size_t)TRELS * D * D * 2);
  size_t o_agg  = align256(o_wn + (size_t)NTYPES * D * D * 2);
  size_t o_hw   = align256(o_agg + (size_t)N * D * 4);

  int* cnt = (int*)(ws + o_cnt);
  int* misc = (int*)(ws + o_misc);
  int* doff = (int*)(ws + o_doff);
  int* dcur = (int*)(ws + o_dcur);
  int* edst = (int*)(ws + o_edst);
  int* nsorted = (int*)(ws + o_ns);
  unsigned short* featsbf = (unsigned short*)(ws + o_fb);
  unsigned short* WeT = (unsigned short*)(ws + o_we);
  unsigned short* WnT = (unsigned short*)(ws + o_wn);
  float* agg = (float*)(ws + o_agg);
  unsigned short* hW = (unsigned short*)(ws + o_hw);
  int* bsum = misc + 64;

  hipMemsetAsync(ws, 0, zend, stream);

  int nfeat = N * D;
  int ptot = nfeat + TRELS * D * D + NTYPES * D * D;
  prep_k<<<(ptot + 255) / 256, 256, 0, stream>>>(feats, W_edge, W_node, featsbf, WeT, WnT, nfeat);

  int hgrid = ((E > N ? E : N) + 255) / 256;
  hist_k<<<hgrid, 256, 0, stream>>>(dst, etypes, ntypes, E, N, cnt, misc + 26);

  int nb = (N + 1023) / 1024;
  scan1_k<<<nb, 256, 0, stream>>>(cnt, doff, bsum, N);
  scan2_k<<<1, 64, 0, stream>>>(misc, bsum, nb);
  scan3_k<<<nb, 256, 0, stream>>>(doff, dcur, bsum, N, E);

  scatter_k<<<hgrid, 256, 0, stream>>>(src, dst, etypes, ntypes, E, N, misc, dcur, edst, nsorted);

  int mtiles = (N + 127) / 128;
  dim3 ggrid(mtiles, TRELS);
  hw_gemm_k<<<ggrid, 256, 0, stream>>>(featsbf, WeT, hW, N);

  agg_k<<<(N + 3) / 4, 256, 0, stream>>>(hW, b_edge, cnt, doff, edst, agg, N);

  int ngrid = mtiles + NTYPES;
  node_gemm_k<<<ngrid, 256, 0, stream>>>(featsbf, WnT, b_node, nsorted, misc, agg, (float*)d_out);
}